// Round 1
// baseline (5134.288 us; speedup 1.0000x reference)
//
#include <hip/hip_runtime.h>

constexpr int H = 128;   // hidden width (all layer outputs)

// ---------------- GEMM: C[M,128] = A[M,K] @ B[K,128] (+bias | +=C) ----------
__global__ __launch_bounds__(256) void sgemm_k(
    const float* __restrict__ A, const float* __restrict__ B,
    const float* __restrict__ bias, float* __restrict__ C,
    int M, int K, int accumulate)
{
  __shared__ float As[16][68];
  __shared__ float Bs[16][68];
  const int tid = threadIdx.x;
  const int tx = tid & 15, ty = tid >> 4;
  const int rowBase = blockIdx.y * 64;
  const int colBase = blockIdx.x * 64;

  const int arow  = tid >> 2;        // 0..63
  const int akoff = (tid & 3) * 4;   // 0,4,8,12
  const int brow  = tid >> 4;        // 0..15
  const int bcol  = (tid & 15) * 4;  // 0..60

  float acc[4][4] = {};

  for (int k0 = 0; k0 < K; k0 += 16) {
    float4 av = make_float4(0.f, 0.f, 0.f, 0.f);
    const int grow = rowBase + arow;
    if (grow < M)
      av = *(const float4*)(A + (size_t)grow * K + k0 + akoff);
    const float4 bv = *(const float4*)(B + (size_t)(k0 + brow) * H + colBase + bcol);
    __syncthreads();   // previous iteration's LDS reads must finish
    As[akoff + 0][arow] = av.x;
    As[akoff + 1][arow] = av.y;
    As[akoff + 2][arow] = av.z;
    As[akoff + 3][arow] = av.w;
    *(float4*)&Bs[brow][bcol] = bv;
    __syncthreads();
#pragma unroll
    for (int k = 0; k < 16; ++k) {
      const float4 a4 = *(const float4*)&As[k][ty * 4];
      const float4 b4 = *(const float4*)&Bs[k][tx * 4];
      const float a[4] = {a4.x, a4.y, a4.z, a4.w};
      const float b[4] = {b4.x, b4.y, b4.z, b4.w};
#pragma unroll
      for (int i = 0; i < 4; ++i)
#pragma unroll
        for (int j = 0; j < 4; ++j)
          acc[i][j] = fmaf(a[i], b[j], acc[i][j]);
    }
  }

#pragma unroll
  for (int i = 0; i < 4; ++i) {
    const int row = rowBase + ty * 4 + i;
    if (row >= M) continue;
    float* cp = C + (size_t)row * H + colBase + tx * 4;
    float4 v = make_float4(acc[i][0], acc[i][1], acc[i][2], acc[i][3]);
    if (accumulate) {
      const float4 o = *(const float4*)cp;
      v.x += o.x; v.y += o.y; v.z += o.z; v.w += o.w;
    } else if (bias) {
      const float* bp = bias + colBase + tx * 4;
      v.x += bp[0]; v.y += bp[1]; v.z += bp[2]; v.w += bp[3];
    }
    *(float4*)cp = v;
  }
}

// -------- edge scatter: agg[dst[e]] += tmp[src[e]] for etype[e]==r ----------
__global__ __launch_bounds__(256) void scatter_rel_k(
    const float* __restrict__ tmp, const int* __restrict__ src,
    const int* __restrict__ dst, const int* __restrict__ et,
    int E, int r, float* __restrict__ agg)
{
  const int wave = (blockIdx.x * 256 + threadIdx.x) >> 6;
  const int lane = threadIdx.x & 63;
  const int nw = (gridDim.x * 256) >> 6;
  for (int e = wave; e < E; e += nw) {
    if (et[e] != r) continue;
    const int s = src[e], d = dst[e];
    const float2 v = ((const float2*)(tmp + (size_t)s * H))[lane];
    float* dr = agg + (size_t)d * H + lane * 2;
    atomicAdd(dr,     v.x);
    atomicAdd(dr + 1, v.y);
  }
}

// ---------------------------- BN helpers ------------------------------------
__global__ void zero_k(float* p, int n) {
  const int i = blockIdx.x * 256 + threadIdx.x;
  if (i < n) p[i] = 0.f;
}

__global__ __launch_bounds__(256) void bn_stats_k(
    const float* __restrict__ X, int Nn, float* __restrict__ stats)
{
  const int col  = threadIdx.x & 127;
  const int half = threadIdx.x >> 7;   // 0/1
  float s = 0.f, q = 0.f;
  for (int row = blockIdx.x * 2 + half; row < Nn; row += gridDim.x * 2) {
    const float v = X[(size_t)row * H + col];
    s += v; q += v * v;
  }
  __shared__ float ls[256], lq[256];
  ls[threadIdx.x] = s; lq[threadIdx.x] = q;
  __syncthreads();
  if (threadIdx.x < 128) {
    atomicAdd(&stats[col],     ls[threadIdx.x] + ls[threadIdx.x + 128]);
    atomicAdd(&stats[H + col], lq[threadIdx.x] + lq[threadIdx.x + 128]);
  }
}

__global__ __launch_bounds__(256) void bn_apply_k(
    const float* __restrict__ X, const float* __restrict__ stats,
    const float* __restrict__ gamma, const float* __restrict__ beta,
    float* __restrict__ Y, int Nn, int relu)
{
  const size_t i = (size_t)blockIdx.x * 256 + threadIdx.x;
  const size_t total = (size_t)Nn * H;
  if (i >= total) return;
  const int col = (int)(i & 127);
  const float mu  = stats[col] / Nn;
  const float var = stats[H + col] / Nn - mu * mu;
  const float inv = rsqrtf(var + 1e-5f);
  float v = fmaf(gamma[col] * inv, X[i] - mu, beta[col]);
  if (relu) v = fmaxf(v, 0.f);
  Y[i] = v;
}

// ---------------------------------------------------------------------------
extern "C" void kernel_launch(void* const* d_in, const int* in_sizes, int n_in,
                              void* d_out, int out_size, void* d_ws, size_t ws_size,
                              hipStream_t stream)
{
  const float* x     = (const float*)d_in[0];
  const int*   src   = (const int*)d_in[1];
  const int*   dst   = (const int*)d_in[2];
  const int*   et    = (const int*)d_in[3];
  const float* W0    = (const float*)d_in[4];
  const float* loop0 = (const float*)d_in[5];
  const float* b0    = (const float*)d_in[6];
  const float* g0    = (const float*)d_in[7];
  const float* be0   = (const float*)d_in[8];
  const float* Ws    = (const float*)d_in[9];
  const float* loops = (const float*)d_in[10];
  const float* bs    = (const float*)d_in[11];
  const float* gs    = (const float*)d_in[12];
  const float* bes   = (const float*)d_in[13];
  const float* Wl    = (const float*)d_in[14];
  const float* bl    = (const float*)d_in[15];
  const float* gl    = (const float*)d_in[16];
  const float* bel   = (const float*)d_in[17];

  const int E = in_sizes[1];
  const int F_in = 64;
  const int N = in_sizes[0] / F_in;
  const int R = in_sizes[4] / (F_in * H);
  const int L = in_sizes[9] / (R * H * H);

  float* h     = (float*)d_out;            // N*H, doubles as inter-layer buffer
  float* agg   = (float*)d_ws;             // N*H
  float* tmp   = agg + (size_t)N * H;      // N*H
  float* stats = tmp + (size_t)N * H;      // 2*H

  const dim3 ggrid(H / 64, (N + 63) / 64);
  const size_t tot = (size_t)N * H;
  const int apply_blocks = (int)((tot + 255) / 256);

  auto run_conv = [&](const float* in, int K, const float* Wr, const float* loopW,
                      const float* bias, const float* gamma, const float* beta) {
    // agg = in @ loopW + bias
    hipLaunchKernelGGL(sgemm_k, ggrid, dim3(256), 0, stream,
                       in, loopW, bias, agg, N, K, 0);
    for (int r = 0; r < R; ++r) {
      hipLaunchKernelGGL(sgemm_k, ggrid, dim3(256), 0, stream,
                         in, Wr + (size_t)r * K * H, (const float*)nullptr, tmp, N, K, 0);
      hipLaunchKernelGGL(scatter_rel_k, dim3(2048), dim3(256), 0, stream,
                         tmp, src, dst, et, E, r, agg);
    }
    hipLaunchKernelGGL(zero_k, dim3(1), dim3(256), 0, stream, stats, 2 * H);
    hipLaunchKernelGGL(bn_stats_k, dim3(512), dim3(256), 0, stream, agg, N, stats);
    hipLaunchKernelGGL(bn_apply_k, dim3(apply_blocks), dim3(256), 0, stream,
                       agg, stats, gamma, beta, h, N, 1);
  };

  run_conv(x, F_in, W0, loop0, b0, g0, be0);
  for (int l = 0; l < L; ++l)
    run_conv(h, H, Ws + (size_t)l * R * H * H, loops + (size_t)l * H * H,
             bs + l * H, gs + l * H, bes + l * H);

  // last layer: h @ Wl + bl, BN without ReLU
  hipLaunchKernelGGL(sgemm_k, ggrid, dim3(256), 0, stream, h, Wl, bl, tmp, N, H, 0);
  hipLaunchKernelGGL(zero_k, dim3(1), dim3(256), 0, stream, stats, 2 * H);
  hipLaunchKernelGGL(bn_stats_k, dim3(512), dim3(256), 0, stream, tmp, N, stats);
  hipLaunchKernelGGL(bn_apply_k, dim3(apply_blocks), dim3(256), 0, stream,
                     tmp, stats, gl, bel, h, N, 0);
}

// Round 2
// 1667.266 us; speedup vs baseline: 3.0795x; 3.0795x over previous
//
#include <hip/hip_runtime.h>

constexpr int H = 128;   // hidden width (all layer outputs)

// ---------------- GEMM: C[M,128] = A[M,K] @ B[K,128] (+bias) ----------------
__global__ __launch_bounds__(256) void sgemm_k(
    const float* __restrict__ A, const float* __restrict__ B,
    const float* __restrict__ bias, float* __restrict__ C,
    int M, int K)
{
  __shared__ float As[16][68];
  __shared__ float Bs[16][68];
  const int tid = threadIdx.x;
  const int tx = tid & 15, ty = tid >> 4;
  const int rowBase = blockIdx.y * 64;
  const int colBase = blockIdx.x * 64;

  const int arow  = tid >> 2;        // 0..63
  const int akoff = (tid & 3) * 4;   // 0,4,8,12
  const int brow  = tid >> 4;        // 0..15
  const int bcol  = (tid & 15) * 4;  // 0..60

  float acc[4][4] = {};

  for (int k0 = 0; k0 < K; k0 += 16) {
    float4 av = make_float4(0.f, 0.f, 0.f, 0.f);
    const int grow = rowBase + arow;
    if (grow < M)
      av = *(const float4*)(A + (size_t)grow * K + k0 + akoff);
    const float4 bv = *(const float4*)(B + (size_t)(k0 + brow) * H + colBase + bcol);
    __syncthreads();
    As[akoff + 0][arow] = av.x;
    As[akoff + 1][arow] = av.y;
    As[akoff + 2][arow] = av.z;
    As[akoff + 3][arow] = av.w;
    *(float4*)&Bs[brow][bcol] = bv;
    __syncthreads();
#pragma unroll
    for (int k = 0; k < 16; ++k) {
      const float4 a4 = *(const float4*)&As[k][ty * 4];
      const float4 b4 = *(const float4*)&Bs[k][tx * 4];
      const float a[4] = {a4.x, a4.y, a4.z, a4.w};
      const float b[4] = {b4.x, b4.y, b4.z, b4.w};
#pragma unroll
      for (int i = 0; i < 4; ++i)
#pragma unroll
        for (int j = 0; j < 4; ++j)
          acc[i][j] = fmaf(a[i], b[j], acc[i][j]);
    }
  }

#pragma unroll
  for (int i = 0; i < 4; ++i) {
    const int row = rowBase + ty * 4 + i;
    if (row >= M) continue;
    float* cp = C + (size_t)row * H + colBase + tx * 4;
    float4 v = make_float4(acc[i][0], acc[i][1], acc[i][2], acc[i][3]);
    if (bias) {
      const float* bp = bias + colBase + tx * 4;
      v.x += bp[0]; v.y += bp[1]; v.z += bp[2]; v.w += bp[3];
    }
    *(float4*)cp = v;
  }
}

// ----------------------------- CSR build ------------------------------------
__global__ void zero_int_k(int* p, int n) {
  const int i = blockIdx.x * 256 + threadIdx.x;
  if (i < n) p[i] = 0;
}

__global__ __launch_bounds__(256) void hist_k(const int* __restrict__ dst, int E,
                                              int* __restrict__ counts) {
  const int e = blockIdx.x * 256 + threadIdx.x;
  if (e < E) atomicAdd(&counts[dst[e]], 1);
}

// per-block exclusive scan (256 elems/block) + block totals
__global__ __launch_bounds__(256) void scan1_k(const int* __restrict__ counts,
                                               int* __restrict__ rowp,
                                               int* __restrict__ partials, int n) {
  __shared__ int s[256];
  const int t = threadIdx.x, i = blockIdx.x * 256 + t;
  const int x = (i < n) ? counts[i] : 0;
  s[t] = x; __syncthreads();
  for (int off = 1; off < 256; off <<= 1) {
    const int v = (t >= off) ? s[t - off] : 0;
    __syncthreads(); s[t] += v; __syncthreads();
  }
  if (i < n) rowp[i] = s[t] - x;           // exclusive within block
  if (t == 255) partials[blockIdx.x] = s[255];
}

__global__ __launch_bounds__(512) void scan2_k(int* partials, int nb) {
  __shared__ int s[512];
  const int t = threadIdx.x;
  const int x = (t < nb) ? partials[t] : 0;
  s[t] = x; __syncthreads();
  for (int off = 1; off < 512; off <<= 1) {
    const int v = (t >= off) ? s[t - off] : 0;
    __syncthreads(); s[t] += v; __syncthreads();
  }
  if (t < nb) partials[t] = s[t] - x;      // exclusive block offsets
}

__global__ __launch_bounds__(256) void scan3_k(int* __restrict__ rowp,
                                               int* __restrict__ cursor,
                                               const int* __restrict__ partials,
                                               int n, int E) {
  const int i = blockIdx.x * 256 + threadIdx.x;
  if (i < n) {
    const int v = rowp[i] + partials[i >> 8];
    rowp[i] = v; cursor[i] = v;
  }
  if (i == 0) rowp[n] = E;
}

__global__ __launch_bounds__(256) void pack_k(const int* __restrict__ src,
                                              const int* __restrict__ dst,
                                              const int* __restrict__ et, int E,
                                              int* __restrict__ cursor,
                                              int* __restrict__ ep) {
  const int e = blockIdx.x * 256 + threadIdx.x;
  if (e < E) {
    const int pos = atomicAdd(&cursor[dst[e]], 1);
    ep[pos] = (et[e] << 20) | src[e];      // N=100000 < 2^20, R=4 fits above
  }
}

// -------- CSR gather: agg[n] += sum_{e in-edges(n)} tmp_all[et][src] --------
__global__ __launch_bounds__(256) void gather_csr_k(
    const float* __restrict__ tmp_all, const int* __restrict__ rowp,
    const int* __restrict__ ep, float* __restrict__ agg, int Nn)
{
  const int node = (blockIdx.x * 256 + threadIdx.x) >> 6;
  const int lane = threadIdx.x & 63;
  if (node >= Nn) return;
  const int beg = rowp[node], end = rowp[node + 1];
  float2 acc = ((const float2*)(agg + (size_t)node * H))[lane];  // self-loop init
  int e = beg;
  for (; e + 1 < end; e += 2) {
    const int p0 = ep[e], p1 = ep[e + 1];
    const float2 v0 = ((const float2*)(tmp_all + ((size_t)(p0 >> 20) * Nn + (p0 & 0xFFFFF)) * H))[lane];
    const float2 v1 = ((const float2*)(tmp_all + ((size_t)(p1 >> 20) * Nn + (p1 & 0xFFFFF)) * H))[lane];
    acc.x += v0.x + v1.x; acc.y += v0.y + v1.y;
  }
  if (e < end) {
    const int p = ep[e];
    const float2 v = ((const float2*)(tmp_all + ((size_t)(p >> 20) * Nn + (p & 0xFFFFF)) * H))[lane];
    acc.x += v.x; acc.y += v.y;
  }
  ((float2*)(agg + (size_t)node * H))[lane] = acc;
}

// ---- fallback atomic scatter (only if ws_size too small for CSR path) ------
__global__ __launch_bounds__(256) void scatter_rel_k(
    const float* __restrict__ tmp, const int* __restrict__ src,
    const int* __restrict__ dst, const int* __restrict__ et,
    int E, int r, float* __restrict__ agg)
{
  const int wave = (blockIdx.x * 256 + threadIdx.x) >> 6;
  const int lane = threadIdx.x & 63;
  const int nw = (gridDim.x * 256) >> 6;
  for (int e = wave; e < E; e += nw) {
    if (et[e] != r) continue;
    const int s = src[e], d = dst[e];
    const float2 v = ((const float2*)(tmp + (size_t)s * H))[lane];
    float* dr = agg + (size_t)d * H + lane * 2;
    atomicAdd(dr, v.x);
    atomicAdd(dr + 1, v.y);
  }
}

// ---------------------------- BN helpers ------------------------------------
__global__ void zero_k(float* p, int n) {
  const int i = blockIdx.x * 256 + threadIdx.x;
  if (i < n) p[i] = 0.f;
}

__global__ __launch_bounds__(256) void bn_stats_k(
    const float* __restrict__ X, int Nn, float* __restrict__ stats)
{
  const int col  = threadIdx.x & 127;
  const int half = threadIdx.x >> 7;
  float s = 0.f, q = 0.f;
  for (int row = blockIdx.x * 2 + half; row < Nn; row += gridDim.x * 2) {
    const float v = X[(size_t)row * H + col];
    s += v; q += v * v;
  }
  __shared__ float ls[256], lq[256];
  ls[threadIdx.x] = s; lq[threadIdx.x] = q;
  __syncthreads();
  if (threadIdx.x < 128) {
    atomicAdd(&stats[col],     ls[threadIdx.x] + ls[threadIdx.x + 128]);
    atomicAdd(&stats[H + col], lq[threadIdx.x] + lq[threadIdx.x + 128]);
  }
}

__global__ __launch_bounds__(256) void bn_apply_k(
    const float* __restrict__ X, const float* __restrict__ stats,
    const float* __restrict__ gamma, const float* __restrict__ beta,
    float* __restrict__ Y, int Nn, int relu)
{
  const size_t i = (size_t)blockIdx.x * 256 + threadIdx.x;
  const size_t total = (size_t)Nn * H;
  if (i >= total) return;
  const int col = (int)(i & 127);
  const float mu  = stats[col] / Nn;
  const float var = stats[H + col] / Nn - mu * mu;
  const float inv = rsqrtf(var + 1e-5f);
  float v = fmaf(gamma[col] * inv, X[i] - mu, beta[col]);
  if (relu) v = fmaxf(v, 0.f);
  Y[i] = v;
}

// ---------------------------------------------------------------------------
extern "C" void kernel_launch(void* const* d_in, const int* in_sizes, int n_in,
                              void* d_out, int out_size, void* d_ws, size_t ws_size,
                              hipStream_t stream)
{
  const float* x     = (const float*)d_in[0];
  const int*   src   = (const int*)d_in[1];
  const int*   dst   = (const int*)d_in[2];
  const int*   et    = (const int*)d_in[3];
  const float* W0    = (const float*)d_in[4];
  const float* loop0 = (const float*)d_in[5];
  const float* b0    = (const float*)d_in[6];
  const float* g0    = (const float*)d_in[7];
  const float* be0   = (const float*)d_in[8];
  const float* Ws    = (const float*)d_in[9];
  const float* loops = (const float*)d_in[10];
  const float* bs    = (const float*)d_in[11];
  const float* gs    = (const float*)d_in[12];
  const float* bes   = (const float*)d_in[13];
  const float* Wl    = (const float*)d_in[14];
  const float* bl    = (const float*)d_in[15];
  const float* gl    = (const float*)d_in[16];
  const float* bel   = (const float*)d_in[17];

  const int E = in_sizes[1];
  const int F_in = 64;
  const int N = in_sizes[0] / F_in;
  const int R = in_sizes[4] / (F_in * H);
  const int L = in_sizes[9] / (R * H * H);

  float* h = (float*)d_out;                     // N*H inter-layer buffer

  const dim3 ggrid(H / 64, (N + 63) / 64);
  const size_t tot = (size_t)N * H;
  const int apply_blocks = (int)((tot + 255) / 256);
  const int eblocks = (E + 255) / 256;
  const int nblocks = (N + 255) / 256;          // also the scan1 block count

  // ---- workspace layout (CSR fast path) ----
  const size_t nTmpAll = (size_t)R * N * H;     // R relation transforms
  const size_t nAgg    = (size_t)N * H;
  float* tmp_all = (float*)d_ws;
  float* agg     = tmp_all + nTmpAll;
  float* stats   = agg + nAgg;                  // 2*H
  int*   counts  = (int*)(stats + 2 * H);
  int*   rowp    = counts + N;                  // N+1
  int*   cursor  = rowp + (N + 1);
  int*   partials= cursor + N;                  // up to 512
  int*   ep      = partials + 512;              // E packed edges
  const size_t needed = ((char*)(ep + E)) - (char*)d_ws;
  const bool fast = ws_size >= needed && N < (1 << 20) && R <= 8 && nblocks <= 512;

  auto run_bn = [&](const float* in, const float* gamma, const float* beta, int relu) {
    hipLaunchKernelGGL(zero_k, dim3(1), dim3(256), 0, stream, stats, 2 * H);
    hipLaunchKernelGGL(bn_stats_k, dim3(512), dim3(256), 0, stream, in, N, stats);
    hipLaunchKernelGGL(bn_apply_k, dim3(apply_blocks), dim3(256), 0, stream,
                       in, stats, gamma, beta, h, N, relu);
  };

  if (fast) {
    // ---- build dst-CSR once ----
    hipLaunchKernelGGL(zero_int_k, dim3(nblocks), dim3(256), 0, stream, counts, N);
    hipLaunchKernelGGL(hist_k, dim3(eblocks), dim3(256), 0, stream, dst, E, counts);
    hipLaunchKernelGGL(scan1_k, dim3(nblocks), dim3(256), 0, stream, counts, rowp, partials, N);
    hipLaunchKernelGGL(scan2_k, dim3(1), dim3(512), 0, stream, partials, nblocks);
    hipLaunchKernelGGL(scan3_k, dim3(nblocks + 1), dim3(256), 0, stream, rowp, cursor, partials, N, E);
    hipLaunchKernelGGL(pack_k, dim3(eblocks), dim3(256), 0, stream, src, dst, et, E, cursor, ep);

    auto run_conv = [&](const float* in, int K, const float* Wr, const float* loopW,
                        const float* bias, const float* gamma, const float* beta) {
      for (int r = 0; r < R; ++r)
        hipLaunchKernelGGL(sgemm_k, ggrid, dim3(256), 0, stream,
                           in, Wr + (size_t)r * K * H, (const float*)nullptr,
                           tmp_all + (size_t)r * N * H, N, K);
      hipLaunchKernelGGL(sgemm_k, ggrid, dim3(256), 0, stream,
                         in, loopW, bias, agg, N, K);
      hipLaunchKernelGGL(gather_csr_k, dim3((N + 3) / 4), dim3(256), 0, stream,
                         tmp_all, rowp, ep, agg, N);
      run_bn(agg, gamma, beta, 1);
    };

    run_conv(x, F_in, W0, loop0, b0, g0, be0);
    for (int l = 0; l < L; ++l)
      run_conv(h, H, Ws + (size_t)l * R * H * H, loops + (size_t)l * H * H,
               bs + l * H, gs + l * H, bes + l * H);

    hipLaunchKernelGGL(sgemm_k, ggrid, dim3(256), 0, stream, h, Wl, bl, tmp_all, N, H);
    run_bn(tmp_all, gl, bel, 0);
  } else {
    // ---- fallback: atomic scatter path (R0 structure) ----
    float* aggf = (float*)d_ws;
    float* tmpf = aggf + nAgg;
    float* statf = tmpf + nAgg;
    auto run_bnf = [&](const float* in, const float* gamma, const float* beta, int relu) {
      hipLaunchKernelGGL(zero_k, dim3(1), dim3(256), 0, stream, statf, 2 * H);
      hipLaunchKernelGGL(bn_stats_k, dim3(512), dim3(256), 0, stream, in, N, statf);
      hipLaunchKernelGGL(bn_apply_k, dim3(apply_blocks), dim3(256), 0, stream,
                         in, statf, gamma, beta, h, N, relu);
    };
    auto run_conv = [&](const float* in, int K, const float* Wr, const float* loopW,
                        const float* bias, const float* gamma, const float* beta) {
      hipLaunchKernelGGL(sgemm_k, ggrid, dim3(256), 0, stream, in, loopW, bias, aggf, N, K);
      for (int r = 0; r < R; ++r) {
        hipLaunchKernelGGL(sgemm_k, ggrid, dim3(256), 0, stream,
                           in, Wr + (size_t)r * K * H, (const float*)nullptr, tmpf, N, K);
        hipLaunchKernelGGL(scatter_rel_k, dim3(2048), dim3(256), 0, stream,
                           tmpf, src, dst, et, E, r, aggf);
      }
      run_bnf(aggf, gamma, beta, 1);
    };
    run_conv(x, F_in, W0, loop0, b0, g0, be0);
    for (int l = 0; l < L; ++l)
      run_conv(h, H, Ws + (size_t)l * R * H * H, loops + (size_t)l * H * H,
               bs + l * H, gs + l * H, bes + l * H);
    hipLaunchKernelGGL(sgemm_k, ggrid, dim3(256), 0, stream, h, Wl, bl, tmpf, N, H);
    run_bnf(tmpf, gl, bel, 0);
  }
}

// Round 3
// 994.556 us; speedup vs baseline: 5.1624x; 1.6764x over previous
//
#include <hip/hip_runtime.h>

constexpr int H = 128;   // hidden width (all layer outputs)

typedef __attribute__((ext_vector_type(8))) __bf16 bf16x8;
typedef __attribute__((ext_vector_type(4))) float  f32x4;

__device__ __forceinline__ unsigned short f2bf(float f) {
  unsigned u = __builtin_bit_cast(unsigned, f);
  u += 0x7FFFu + ((u >> 16) & 1u);          // RNE
  return (unsigned short)(u >> 16);
}
__device__ __forceinline__ float bf2f(unsigned short b) {
  unsigned u = ((unsigned)b) << 16;
  return __builtin_bit_cast(float, u);
}

// ---------------- fp32 -> bf16 elementwise convert --------------------------
__global__ __launch_bounds__(256) void conv_bf_k(const float* __restrict__ in,
                                                 unsigned short* __restrict__ out,
                                                 long n) {
  const long i = (long)blockIdx.x * 256 + threadIdx.x;
  if (i < n) out[i] = f2bf(in[i]);
}

// ------- pack weights [nRel blocks of K*H] + loopW[K*H] into B-frag layout --
// Bpre[((Ct*kSteps + s)*64 + lane)*8 + j] = W[k = s*32 + (lane>>4)*8 + j][col]
// where col = Ct*16 + (lane&15); group g = col>>7 selects W_rel[g] or loopW.
__global__ __launch_bounds__(256) void prep_w_k(
    const float* __restrict__ Wr, const float* __restrict__ loopW,
    unsigned short* __restrict__ Bpre, int K, int colTiles, int nRel)
{
  const int idx = blockIdx.x * 256 + threadIdx.x;
  const int kSteps = K / 32;
  const int total = colTiles * kSteps * 64;
  if (idx >= total) return;
  const int lane = idx & 63;
  const int s    = (idx >> 6) % kSteps;
  const int Ct   = idx / (kSteps * 64);
  const int col  = Ct * 16 + (lane & 15);
  const int g    = col >> 7;
  const int cg   = col & 127;
  const float* src = (g < nRel) ? (Wr + (size_t)g * K * H + cg)
                                : (loopW + cg);
  const int k0 = s * 32 + (lane >> 4) * 8;
  unsigned short v[8];
#pragma unroll
  for (int j = 0; j < 8; ++j) v[j] = f2bf(src[(size_t)(k0 + j) * H]);
  unsigned short* dst = Bpre + (size_t)(((Ct * kSteps + s) * 64 + lane)) * 8;
  *(uint4*)dst = *(uint4*)v;
}

// ---------------- fused MFMA GEMM: C[M, groups*128] = A[M,K] @ Bpre ---------
// blockIdx.x = col group (128 cols). groups < fpGroup -> bf16 into tmp_all;
// group == fpGroup -> fp32 into agg with bias.
__global__ __launch_bounds__(256) void mfma_gemm_k(
    const unsigned short* __restrict__ Abf,   // [M][K] bf16 row-major
    const unsigned short* __restrict__ Bpre,
    const float* __restrict__ bias,
    unsigned short* __restrict__ tmp_all,     // [fpGroup][M][H] bf16
    float* __restrict__ agg,                  // [M][H] fp32
    int M, int K, int fpGroup)
{
  extern __shared__ unsigned short Alds[];    // [128][K+8]
  const int strideL = K + 8;
  const int tid = threadIdx.x;
  const int rowBase = blockIdx.y * 128;
  const int kSteps = K / 32;

  // ---- stage A tile (128 x K) into LDS ----
  const int cpr = K / 8;                      // 16B chunks per row
  const int cshift = (cpr == 16) ? 4 : 3;
  const int totalChunks = 128 * cpr;
  for (int c = tid; c < totalChunks; c += 256) {
    const int row = c >> cshift;
    const int kc  = c & (cpr - 1);
    const int grow = rowBase + row;
    uint4 v = make_uint4(0, 0, 0, 0);
    if (grow < M) v = *(const uint4*)(Abf + (size_t)grow * K + kc * 8);
    *(uint4*)(Alds + (size_t)row * strideL + kc * 8) = v;
  }
  __syncthreads();

  const int wave = tid >> 6, lane = tid & 63;
  const int quad = lane >> 4, l15 = lane & 15;

  f32x4 acc[2][8] = {};
  const size_t bBase = ((size_t)blockIdx.x * 8) * kSteps * 64 * 8;

  for (int s = 0; s < kSteps; ++s) {
    bf16x8 a[2];
#pragma unroll
    for (int rt = 0; rt < 2; ++rt) {
      const int row = wave * 32 + rt * 16 + l15;
      a[rt] = *(const bf16x8*)(Alds + (size_t)row * strideL + s * 32 + quad * 8);
    }
#pragma unroll
    for (int c = 0; c < 8; ++c) {
      const bf16x8 b = *(const bf16x8*)(Bpre + bBase +
                        (size_t)((c * kSteps + s) * 64 + lane) * 8);
      acc[0][c] = __builtin_amdgcn_mfma_f32_16x16x32_bf16(a[0], b, acc[0][c], 0, 0, 0);
      acc[1][c] = __builtin_amdgcn_mfma_f32_16x16x32_bf16(a[1], b, acc[1][c], 0, 0, 0);
    }
  }

  // ---- epilogue: D row = quad*4+reg, col = l15 (within 16x16 tile) ----
  const int g = blockIdx.x;
  if (g < fpGroup) {
    unsigned short* outp = tmp_all + (size_t)g * M * H;
#pragma unroll
    for (int rt = 0; rt < 2; ++rt)
#pragma unroll
      for (int reg = 0; reg < 4; ++reg) {
        const int row = rowBase + wave * 32 + rt * 16 + quad * 4 + reg;
        if (row >= M) continue;
#pragma unroll
        for (int c = 0; c < 8; ++c)
          outp[(size_t)row * H + c * 16 + l15] = f2bf(acc[rt][c][reg]);
      }
  } else {
#pragma unroll
    for (int rt = 0; rt < 2; ++rt)
#pragma unroll
      for (int reg = 0; reg < 4; ++reg) {
        const int row = rowBase + wave * 32 + rt * 16 + quad * 4 + reg;
        if (row >= M) continue;
#pragma unroll
        for (int c = 0; c < 8; ++c) {
          const int col = c * 16 + l15;
          agg[(size_t)row * H + col] = acc[rt][c][reg] + bias[col];
        }
      }
  }
}

// ----------------------------- CSR build ------------------------------------
__global__ void zero_int_k(int* p, int n) {
  const int i = blockIdx.x * 256 + threadIdx.x;
  if (i < n) p[i] = 0;
}

__global__ __launch_bounds__(256) void hist_k(const int* __restrict__ dst, int E,
                                              int* __restrict__ counts) {
  const int e = blockIdx.x * 256 + threadIdx.x;
  if (e < E) atomicAdd(&counts[dst[e]], 1);
}

__global__ __launch_bounds__(256) void scan1_k(const int* __restrict__ counts,
                                               int* __restrict__ rowp,
                                               int* __restrict__ partials, int n) {
  __shared__ int s[256];
  const int t = threadIdx.x, i = blockIdx.x * 256 + t;
  const int x = (i < n) ? counts[i] : 0;
  s[t] = x; __syncthreads();
  for (int off = 1; off < 256; off <<= 1) {
    const int v = (t >= off) ? s[t - off] : 0;
    __syncthreads(); s[t] += v; __syncthreads();
  }
  if (i < n) rowp[i] = s[t] - x;
  if (t == 255) partials[blockIdx.x] = s[255];
}

__global__ __launch_bounds__(512) void scan2_k(int* partials, int nb) {
  __shared__ int s[512];
  const int t = threadIdx.x;
  const int x = (t < nb) ? partials[t] : 0;
  s[t] = x; __syncthreads();
  for (int off = 1; off < 512; off <<= 1) {
    const int v = (t >= off) ? s[t - off] : 0;
    __syncthreads(); s[t] += v; __syncthreads();
  }
  if (t < nb) partials[t] = s[t] - x;
}

__global__ __launch_bounds__(256) void scan3_k(int* __restrict__ rowp,
                                               int* __restrict__ cursor,
                                               const int* __restrict__ partials,
                                               int n, int E) {
  const int i = blockIdx.x * 256 + threadIdx.x;
  if (i < n) {
    const int v = rowp[i] + partials[i >> 8];
    rowp[i] = v; cursor[i] = v;
  }
  if (i == 0) rowp[n] = E;
}

__global__ __launch_bounds__(256) void pack_k(const int* __restrict__ src,
                                              const int* __restrict__ dst,
                                              const int* __restrict__ et, int E,
                                              int* __restrict__ cursor,
                                              int* __restrict__ ep) {
  const int e = blockIdx.x * 256 + threadIdx.x;
  if (e < E) {
    const int pos = atomicAdd(&cursor[dst[e]], 1);
    ep[pos] = (et[e] << 20) | src[e];
  }
}

// ----- CSR gather (bf16 messages): agg[n] += sum tmp_all[et][src] -----------
__global__ __launch_bounds__(256) void gather_csr_k(
    const unsigned short* __restrict__ tmp_all, const int* __restrict__ rowp,
    const int* __restrict__ ep, float* __restrict__ agg, int Nn)
{
  const int node = (blockIdx.x * 256 + threadIdx.x) >> 6;
  const int lane = threadIdx.x & 63;
  if (node >= Nn) return;
  const int beg = rowp[node], end = rowp[node + 1];
  float2 acc = ((const float2*)(agg + (size_t)node * H))[lane];
  int e = beg;
  for (; e + 1 < end; e += 2) {
    const int p0 = ep[e], p1 = ep[e + 1];
    const unsigned v0 = *(const unsigned*)(tmp_all +
        ((size_t)(p0 >> 20) * Nn + (p0 & 0xFFFFF)) * H + lane * 2);
    const unsigned v1 = *(const unsigned*)(tmp_all +
        ((size_t)(p1 >> 20) * Nn + (p1 & 0xFFFFF)) * H + lane * 2);
    acc.x += bf2f((unsigned short)(v0 & 0xFFFF)) + bf2f((unsigned short)(v1 & 0xFFFF));
    acc.y += bf2f((unsigned short)(v0 >> 16))    + bf2f((unsigned short)(v1 >> 16));
  }
  if (e < end) {
    const int p = ep[e];
    const unsigned v = *(const unsigned*)(tmp_all +
        ((size_t)(p >> 20) * Nn + (p & 0xFFFFF)) * H + lane * 2);
    acc.x += bf2f((unsigned short)(v & 0xFFFF));
    acc.y += bf2f((unsigned short)(v >> 16));
  }
  ((float2*)(agg + (size_t)node * H))[lane] = acc;
}

// ---------------------------- BN helpers ------------------------------------
__global__ void zero_k(float* p, int n) {
  const int i = blockIdx.x * 256 + threadIdx.x;
  if (i < n) p[i] = 0.f;
}

__global__ __launch_bounds__(256) void bn_stats_k(
    const float* __restrict__ X, int Nn, float* __restrict__ stats)
{
  const int col  = threadIdx.x & 127;
  const int half = threadIdx.x >> 7;
  float s = 0.f, q = 0.f;
  for (int row = blockIdx.x * 2 + half; row < Nn; row += gridDim.x * 2) {
    const float v = X[(size_t)row * H + col];
    s += v; q += v * v;
  }
  __shared__ float ls[256], lq[256];
  ls[threadIdx.x] = s; lq[threadIdx.x] = q;
  __syncthreads();
  if (threadIdx.x < 128) {
    atomicAdd(&stats[col],     ls[threadIdx.x] + ls[threadIdx.x + 128]);
    atomicAdd(&stats[H + col], lq[threadIdx.x] + lq[threadIdx.x + 128]);
  }
}

// BN apply + ReLU; writes bf16 (next-layer input) or fp32 (final output)
__global__ __launch_bounds__(256) void bn_apply_k(
    const float* __restrict__ X, const float* __restrict__ stats,
    const float* __restrict__ gamma, const float* __restrict__ beta,
    unsigned short* __restrict__ out_bf, float* __restrict__ out_f,
    int Nn, int relu)
{
  const size_t i = (size_t)blockIdx.x * 256 + threadIdx.x;
  const size_t total = (size_t)Nn * H;
  if (i >= total) return;
  const int col = (int)(i & 127);
  const float mu  = stats[col] / Nn;
  const float var = stats[H + col] / Nn - mu * mu;
  const float inv = rsqrtf(var + 1e-5f);
  float v = fmaf(gamma[col] * inv, X[i] - mu, beta[col]);
  if (relu) v = fmaxf(v, 0.f);
  if (out_bf) out_bf[i] = f2bf(v);
  else        out_f[i]  = v;
}

// ---------------------------------------------------------------------------
extern "C" void kernel_launch(void* const* d_in, const int* in_sizes, int n_in,
                              void* d_out, int out_size, void* d_ws, size_t ws_size,
                              hipStream_t stream)
{
  const float* x     = (const float*)d_in[0];
  const int*   src   = (const int*)d_in[1];
  const int*   dst   = (const int*)d_in[2];
  const int*   et    = (const int*)d_in[3];
  const float* W0    = (const float*)d_in[4];
  const float* loop0 = (const float*)d_in[5];
  const float* b0    = (const float*)d_in[6];
  const float* g0    = (const float*)d_in[7];
  const float* be0   = (const float*)d_in[8];
  const float* Ws    = (const float*)d_in[9];
  const float* loops = (const float*)d_in[10];
  const float* bs    = (const float*)d_in[11];
  const float* gs    = (const float*)d_in[12];
  const float* bes   = (const float*)d_in[13];
  const float* Wl    = (const float*)d_in[14];
  const float* bl    = (const float*)d_in[15];
  const float* gl    = (const float*)d_in[16];
  const float* bel   = (const float*)d_in[17];

  const int E = in_sizes[1];
  const int F_in = 64;
  const int N = in_sizes[0] / F_in;
  const int R = in_sizes[4] / (F_in * H);
  const int L = in_sizes[9] / (R * H * H);

  float* outp = (float*)d_out;   // N*H fp32 final output

  // ---- workspace layout ----
  char* p = (char*)d_ws;
  auto alloc = [&](size_t bytes) { char* r = p; p += (bytes + 255) & ~size_t(255); return r; };
  float*          agg     = (float*)alloc((size_t)N * H * 4);
  float*          stats   = (float*)alloc(2 * H * 4);
  unsigned short* tmp_all = (unsigned short*)alloc((size_t)R * N * H * 2);
  unsigned short* hbf     = (unsigned short*)alloc((size_t)N * H * 2);   // activations (bf16)
  unsigned short* Bpre    = (unsigned short*)alloc((size_t)(R + 1) * H * H * 2);
  int*            counts  = (int*)alloc((size_t)N * 4);
  int*            rowp    = (int*)alloc((size_t)(N + 1) * 4);
  int*            cursor  = (int*)alloc((size_t)N * 4);
  int*            partials= (int*)alloc(512 * 4);
  int*            ep      = (int*)alloc((size_t)E * 4);
  (void)ws_size;

  const int eblocks = (E + 255) / 256;
  const int nblocks = (N + 255) / 256;
  const size_t tot = (size_t)N * H;
  const int apply_blocks = (int)((tot + 255) / 256);
  const int rowBlocks = (N + 127) / 128;

  // ---- build dst-CSR once ----
  hipLaunchKernelGGL(zero_int_k, dim3(nblocks), dim3(256), 0, stream, counts, N);
  hipLaunchKernelGGL(hist_k, dim3(eblocks), dim3(256), 0, stream, dst, E, counts);
  hipLaunchKernelGGL(scan1_k, dim3(nblocks), dim3(256), 0, stream, counts, rowp, partials, N);
  hipLaunchKernelGGL(scan2_k, dim3(1), dim3(512), 0, stream, partials, nblocks);
  hipLaunchKernelGGL(scan3_k, dim3(nblocks + 1), dim3(256), 0, stream, rowp, cursor, partials, N, E);
  hipLaunchKernelGGL(pack_k, dim3(eblocks), dim3(256), 0, stream, src, dst, et, E, cursor, ep);

  // ---- convert x to bf16 ----
  {
    const long nx = (long)N * F_in;
    hipLaunchKernelGGL(conv_bf_k, dim3((unsigned)((nx + 255) / 256)), dim3(256), 0, stream,
                       x, hbf, nx);
  }

  auto run_conv = [&](const unsigned short* Abf, int K, const float* Wr,
                      const float* loopW, const float* bias,
                      const float* gamma, const float* beta,
                      unsigned short* hout) {
    const int colTiles = (R + 1) * 8;
    const int kSteps = K / 32;
    const int prepThreads = colTiles * kSteps * 64;
    hipLaunchKernelGGL(prep_w_k, dim3((prepThreads + 255) / 256), dim3(256), 0, stream,
                       Wr, loopW, Bpre, K, colTiles, R);
    const size_t lds = (size_t)128 * (K + 8) * 2;
    hipLaunchKernelGGL(mfma_gemm_k, dim3(R + 1, rowBlocks), dim3(256), lds, stream,
                       Abf, Bpre, bias, tmp_all, agg, N, K, R);
    hipLaunchKernelGGL(gather_csr_k, dim3((N + 3) / 4), dim3(256), 0, stream,
                       tmp_all, rowp, ep, agg, N);
    hipLaunchKernelGGL(zero_k, dim3(1), dim3(256), 0, stream, stats, 2 * H);
    hipLaunchKernelGGL(bn_stats_k, dim3(512), dim3(256), 0, stream, agg, N, stats);
    hipLaunchKernelGGL(bn_apply_k, dim3(apply_blocks), dim3(256), 0, stream,
                       agg, stats, gamma, beta, hout, (float*)nullptr, N, 1);
  };

  // layer 0 (K = F_in): input bf16 currently in hbf (N*F_in), output into hbf (N*H).
  // hbf holds x_bf (N*64) and will be overwritten with h (N*128) by bn_apply —
  // but gather/GEMM read x_bf before bn_apply runs (stream-ordered), and
  // bn_apply writes to a region that fully covers x_bf only after all reads. To
  // be safe, keep x_bf and h in separate halves: reuse tmp_all? No — simplest:
  // allocate x_bf separately (small).
  // NOTE: x_bf was written into hbf above; run layer0 with output into hbf is
  // unsafe (overlap). Instead convert x into the cursor area? cursor is int N —
  // too small. We placed x_bf in hbf; give layer0 its own output into hbf after
  // GEMM+gather+stats complete: bn_apply reads agg only, writes hbf — the GEMM
  // (which read x_bf from hbf) has already completed. Stream order guarantees
  // this. Safe.
  run_conv(hbf, F_in, W0, loop0, b0, g0, be0, hbf);
  for (int l = 0; l < L; ++l)
    run_conv(hbf, H, Ws + (size_t)l * R * H * H, loops + (size_t)l * H * H,
             bs + l * H, gs + l * H, bes + l * H, hbf);

  // ---- final linear: agg = h @ Wl + bl (fp32), then BN (no ReLU) -> d_out --
  {
    const int colTiles = 8, kSteps = H / 32;
    const int prepThreads = colTiles * kSteps * 64;
    hipLaunchKernelGGL(prep_w_k, dim3((prepThreads + 255) / 256), dim3(256), 0, stream,
                       (const float*)nullptr, Wl, Bpre, H, colTiles, 0);
    const size_t lds = (size_t)128 * (H + 8) * 2;
    hipLaunchKernelGGL(mfma_gemm_k, dim3(1, rowBlocks), dim3(256), lds, stream,
                       hbf, Bpre, bl, (unsigned short*)nullptr, agg, N, H, 0);
    hipLaunchKernelGGL(zero_k, dim3(1), dim3(256), 0, stream, stats, 2 * H);
    hipLaunchKernelGGL(bn_stats_k, dim3(512), dim3(256), 0, stream, agg, N, stats);
    hipLaunchKernelGGL(bn_apply_k, dim3(apply_blocks), dim3(256), 0, stream,
                       agg, stats, gl, bel, (unsigned short*)nullptr, outp, N, 0);
  }
}